// Round 9
// baseline (1919.221 us; speedup 1.0000x reference)
//
#include <hip/hip_runtime.h>
#include <math.h>

#define NN 100000
#define EE 500000

// ---------------- RTE sinusoid table [240, 256] ----------------
__global__ void rte_tab_kernel(float* __restrict__ tab) {
    int p = blockIdx.x;      // 0..239
    int j = threadIdx.x;     // 0..255
    int m = j >> 1;
    // replicate fp32 overflow: 10000^(2m) -> inf for 2m >= 10 in fp32
    float pf = (float)pow(10000.0, (double)(2 * m));
    float dv = 1.0f / (pf / 128.0f / 2.0f);
    float ang = (float)p * dv;
    const float s = 0.08838834764831845f; // 1/sqrt(128)
    float v = (j & 1) ? (cosf(ang) * s) : (sinf(ang) * s);
    tab[p * 256 + j] = v;
}

// ---------------- rte_proj[p,c] = rte_tab[p,:] @ rte_w + rte_b ----------------
__global__ void rte_proj_kernel(const float* __restrict__ tab,
                                const float* __restrict__ rte_w,
                                const float* __restrict__ rte_b,
                                float* __restrict__ proj) {
    __shared__ float row[256];
    int p = blockIdx.x;           // 240
    int c = threadIdx.x;          // 128
    for (int i = threadIdx.x; i < 256; i += 128) row[i] = tab[p * 256 + i];
    __syncthreads();
    float acc = rte_b[c];
    #pragma unroll 8
    for (int q = 0; q < 256; ++q) acc += row[q] * rte_w[q * 128 + c];
    proj[p * 128 + c] = acc;
}

// ---------------- ktv[b][0:128]=proj@Wk[t], ktv[b][128:256]=proj@Wv[t] ----------------
__global__ void ktv_kernel(const float* __restrict__ proj,
                           const float* __restrict__ Wk,
                           const float* __restrict__ Wv,
                           float* __restrict__ ktv) {
    __shared__ float row[128];
    int b = blockIdx.x;           // 720 = t*240 + p
    int t = b / 240, p = b % 240;
    int c = threadIdx.x;          // 128
    row[c] = proj[p * 128 + c];
    __syncthreads();
    const float* wk = Wk + t * 16384 + c;
    const float* wv = Wv + t * 16384 + c;
    float ak = 0.f, av = 0.f;
    #pragma unroll 8
    for (int q = 0; q < 128; ++q) {
        float rv = row[q];
        ak += rv * wk[q * 128];
        av += rv * wv[q * 128];
    }
    ktv[(size_t)b * 256 + c] = ak;
    ktv[(size_t)b * 256 + 128 + c] = av;
}

// ---------------- rel_msg transpose to Mtg[((r*8+h)*16+c)*16+i] (32 KB) ----------------
// Built once per layer; epilogue reads it from global (L1-resident) instead of
// LDS -- removes the 8-way-conflicted LDS table reads AND frees 41 KB of LDS.
__global__ void msg_t_kernel(const float* __restrict__ rel_msg, float* __restrict__ mtg) {
    int d = blockIdx.x * 256 + threadIdx.x;   // 8192 total
    int i = d & 15, c = (d >> 4) & 15, rh = d >> 8;
    mtg[d] = rel_msg[rh * 256 + i * 16 + c];
}

// ---------------- CSR build (edges grouped by target) ----------------
__global__ void hist_kernel(const int* __restrict__ tgt, int* __restrict__ cnt) {
    int e = blockIdx.x * blockDim.x + threadIdx.x;
    if (e < EE) atomicAdd(&cnt[tgt[e]], 1);
}

__global__ void scan_kernel(const int* __restrict__ cnt, int* __restrict__ row_start) {
    __shared__ int sdata[1024];
    __shared__ int s_running;
    if (threadIdx.x == 0) s_running = 0;
    __syncthreads();
    for (int base = 0; base < NN; base += 1024) {
        int i = base + (int)threadIdx.x;
        int v = (i < NN) ? cnt[i] : 0;
        sdata[threadIdx.x] = v;
        __syncthreads();
        int acc = v;
        for (int off = 1; off < 1024; off <<= 1) {
            int t = (threadIdx.x >= (unsigned)off) ? sdata[threadIdx.x - off] : 0;
            __syncthreads();
            acc += t;
            sdata[threadIdx.x] = acc;
            __syncthreads();
        }
        int run = s_running;
        if (i < NN) row_start[i] = run + acc - v;   // exclusive
        __syncthreads();
        if (threadIdx.x == 1023) s_running = run + sdata[1023];
        __syncthreads();
    }
    if (threadIdx.x == 0) row_start[NN] = s_running;
}

// scatter + meta fused: meta[pos] = {src, (tb<<6)|(tt<<4)|(st<<2)|r, tgt, 0}
__global__ void scatter_meta_kernel(const int* __restrict__ esrc,
                                    const int* __restrict__ etgt,
                                    const int* __restrict__ etype,
                                    const int* __restrict__ etime,
                                    const int* __restrict__ node_type,
                                    const int* __restrict__ row_start,
                                    int* __restrict__ fill,
                                    int4* __restrict__ meta) {
    int e = blockIdx.x * blockDim.x + threadIdx.x;
    if (e < EE) {
        int tgt = etgt[e];
        int src = esrc[e];
        int r = etype[e];
        int tm = etime[e];
        int st = node_type[src];
        int tt = node_type[tgt];
        int tb = st * 240 + tm;
        int pos = row_start[tgt] + atomicAdd(&fill[tgt], 1);
        meta[pos] = make_int4(src, (tb << 6) | (tt << 4) | (st << 2) | r, tgt, 0);
    }
}

// ---------------- node counting sort by type (3 bins) ----------------
__global__ void node_hist_kernel(const int* __restrict__ nt, int* __restrict__ tcnt) {
    __shared__ int lc[3];
    if (threadIdx.x < 3) lc[threadIdx.x] = 0;
    __syncthreads();
    int i = blockIdx.x * blockDim.x + threadIdx.x;
    if (i < NN) atomicAdd(&lc[nt[i]], 1);
    __syncthreads();
    if (threadIdx.x < 3) atomicAdd(&tcnt[threadIdx.x], lc[threadIdx.x]);
}

__global__ void node_scatter_kernel(const int* __restrict__ nt,
                                    const int* __restrict__ tcnt,
                                    int* __restrict__ fill3,
                                    int* __restrict__ order) {
    __shared__ int lc[3], lbase[3], lfill[3];
    if (threadIdx.x < 3) { lc[threadIdx.x] = 0; lfill[threadIdx.x] = 0; }
    __syncthreads();
    int i = blockIdx.x * blockDim.x + threadIdx.x;
    int t = -1;
    if (i < NN) { t = nt[i]; atomicAdd(&lc[t], 1); }
    __syncthreads();
    if (threadIdx.x < 3) lbase[threadIdx.x] = atomicAdd(&fill3[threadIdx.x], lc[threadIdx.x]);
    __syncthreads();
    if (i < NN) {
        int rank = atomicAdd(&lfill[t], 1);
        int tb = (t == 0) ? 0 : ((t == 1) ? tcnt[0] : tcnt[0] + tcnt[1]);
        order[tb + lbase[t] + rank] = i;
    }
}

// ---------------- typed linear over type-sorted nodes ----------------
template <int MODE>
__global__ __launch_bounds__(256) void typed_lin_kernel(
    const float* __restrict__ in, const int* __restrict__ nt,
    const int* __restrict__ order,
    const float* __restrict__ W, const float* __restrict__ b,
    const float* __restrict__ skip, float* __restrict__ out) {
    __shared__ float xs[32][128];
    __shared__ int rows[32];
    __shared__ int sty[32];
    int nb = blockIdx.x * 32;
    if (threadIdx.x < 32) {
        int r = order[nb + threadIdx.x];
        rows[threadIdx.x] = r;
        sty[threadIdx.x] = nt[r];
    }
    __syncthreads();
    for (int i = threadIdx.x; i < 1024; i += 256) {
        int nl = i >> 5, e4 = i & 31;
        *(float4*)&xs[nl][e4 * 4] = *(const float4*)(in + (size_t)rows[nl] * 128 + e4 * 4);
    }
    __syncthreads();
    int col = threadIdx.x & 127;
    int ng  = (threadIdx.x >> 7) * 16;
    int t0 = sty[ng];
    bool uni = true;
    #pragma unroll
    for (int ii = 1; ii < 16; ++ii) uni &= (sty[ng + ii] == t0);
    if (uni) {
        const float* w = W + t0 * 16384 + col;
        float bv = b[t0 * 128 + col];
        float alpha = (MODE == 1) ? (1.f / (1.f + __expf(-skip[t0]))) : 0.f;
        float acc[16];
        #pragma unroll
        for (int ii = 0; ii < 16; ++ii) acc[ii] = bv;
        for (int k0 = 0; k0 < 128; k0 += 4) {
            float w0 = w[(k0 + 0) * 128];
            float w1 = w[(k0 + 1) * 128];
            float w2 = w[(k0 + 2) * 128];
            float w3 = w[(k0 + 3) * 128];
            #pragma unroll
            for (int ii = 0; ii < 16; ++ii) {
                float4 xv = *(const float4*)&xs[ng + ii][k0];
                acc[ii] += xv.x * w0 + xv.y * w1 + xv.z * w2 + xv.w * w3;
            }
        }
        #pragma unroll
        for (int ii = 0; ii < 16; ++ii) {
            size_t gi = (size_t)rows[ng + ii] * 128 + col;
            if (MODE == 0) out[gi] = tanhf(acc[ii]);
            else           out[gi] = alpha * acc[ii] + (1.f - alpha) * out[gi];
        }
    } else {
        for (int ii = 0; ii < 16; ++ii) {
            int nl = ng + ii;
            int t = sty[nl];
            const float* w = W + t * 16384 + col;
            float acc = b[t * 128 + col];
            #pragma unroll 8
            for (int k = 0; k < 128; ++k) acc += xs[nl][k] * w[k * 128];
            size_t gi = (size_t)rows[nl] * 128 + col;
            if (MODE == 0) out[gi] = tanhf(acc);
            else {
                float alpha = 1.f / (1.f + __expf(-skip[t]));
                out[gi] = alpha * acc + (1.f - alpha) * out[gi];
            }
        }
    }
}

// ---------------- fused Q/K/V typed projections; K/V interleaved per row ----------------
__global__ __launch_bounds__(256) void qkv_kernel(
    const float* __restrict__ x, const int* __restrict__ nt,
    const int* __restrict__ order,
    const float* __restrict__ Wq, const float* __restrict__ bq,
    const float* __restrict__ Wk, const float* __restrict__ bk,
    const float* __restrict__ Wv, const float* __restrict__ bv,
    float* __restrict__ Qn, float* __restrict__ KV) {
    __shared__ float xs[32][128];
    __shared__ int rows[32];
    __shared__ int sty[32];
    int nb = blockIdx.x * 32;
    if (threadIdx.x < 32) {
        int r = order[nb + threadIdx.x];
        rows[threadIdx.x] = r;
        sty[threadIdx.x] = nt[r];
    }
    __syncthreads();
    for (int i = threadIdx.x; i < 1024; i += 256) {
        int nl = i >> 5, e4 = i & 31;
        *(float4*)&xs[nl][e4 * 4] = *(const float4*)(x + (size_t)rows[nl] * 128 + e4 * 4);
    }
    __syncthreads();
    int col = threadIdx.x & 127;
    int ng  = (threadIdx.x >> 7) * 16;
    int t0 = sty[ng];
    bool uni = true;
    #pragma unroll
    for (int ii = 1; ii < 16; ++ii) uni &= (sty[ng + ii] == t0);
    if (uni) {
        const float* wq = Wq + t0 * 16384 + col;
        const float* wk = Wk + t0 * 16384 + col;
        const float* wv = Wv + t0 * 16384 + col;
        float bqv = bq[t0 * 128 + col];
        float bkv = bk[t0 * 128 + col];
        float bvv = bv[t0 * 128 + col];
        float aq[16], ak[16], av[16];
        #pragma unroll
        for (int ii = 0; ii < 16; ++ii) { aq[ii] = bqv; ak[ii] = bkv; av[ii] = bvv; }
        for (int k0 = 0; k0 < 128; k0 += 4) {
            float q0 = wq[(k0 + 0) * 128], q1 = wq[(k0 + 1) * 128];
            float q2 = wq[(k0 + 2) * 128], q3 = wq[(k0 + 3) * 128];
            float k0w = wk[(k0 + 0) * 128], k1w = wk[(k0 + 1) * 128];
            float k2w = wk[(k0 + 2) * 128], k3w = wk[(k0 + 3) * 128];
            float v0 = wv[(k0 + 0) * 128], v1 = wv[(k0 + 1) * 128];
            float v2 = wv[(k0 + 2) * 128], v3 = wv[(k0 + 3) * 128];
            #pragma unroll
            for (int ii = 0; ii < 16; ++ii) {
                float4 xv = *(const float4*)&xs[ng + ii][k0];
                aq[ii] += xv.x * q0 + xv.y * q1 + xv.z * q2 + xv.w * q3;
                ak[ii] += xv.x * k0w + xv.y * k1w + xv.z * k2w + xv.w * k3w;
                av[ii] += xv.x * v0 + xv.y * v1 + xv.z * v2 + xv.w * v3;
            }
        }
        #pragma unroll
        for (int ii = 0; ii < 16; ++ii) {
            size_t row = (size_t)rows[ng + ii];
            Qn[row * 128 + col] = aq[ii];
            KV[row * 256 + col] = ak[ii];
            KV[row * 256 + 128 + col] = av[ii];
        }
    } else {
        for (int ii = 0; ii < 16; ++ii) {
            int nl = ng + ii;
            int t = sty[nl];
            const float* wq = Wq + t * 16384 + col;
            const float* wk = Wk + t * 16384 + col;
            const float* wv = Wv + t * 16384 + col;
            float aq = bq[t * 128 + col];
            float ak = bk[t * 128 + col];
            float av = bv[t * 128 + col];
            #pragma unroll 4
            for (int k = 0; k < 128; ++k) {
                float xv = xs[nl][k];
                aq += xv * wq[k * 128];
                ak += xv * wk[k * 128];
                av += xv * wv[k * 128];
            }
            size_t row = (size_t)rows[nl];
            Qn[row * 128 + col] = aq;
            KV[row * 256 + col] = ak;
            KV[row * 256 + 128 + col] = av;
        }
    }
}

// ---------------- fused score + softmax + aggregation ----------------
// R9 = R8 with the rel_msg table moved from LDS to a pre-transposed GLOBAL
// buffer Mtg (32 KB, L1-resident). Two effects:
//  1. The epilogue's LDS reads -- the source of the constant 23-27M
//     SQ_LDS_BANK_CONFLICT across R3/R4/R7/R8 (bank start = 24r+4h2+8(lane&7)
//     mod 32 -> 8 lanes per 4-bank group = 8-way conflict) -- become
//     global_load_dwordx4 from a cache-hot table. Zero LDS conflicts.
//  2. LDS drops 117120 -> 75776 B -> 2 blocks/CU = 16 waves/CU (was 8),
//     doubling latency hiding for this latency-bound kernel.
// Everything else (pair-prologue, qA layout, score/aggr body) is R8-verbatim.
// No __launch_bounds__ min-waves (R4: (1024,4) forced VGPR=64 -> spills).
__global__ __launch_bounds__(512) void edge_kernel(
    const float* __restrict__ Qn, const float* __restrict__ KV,
    const float* __restrict__ ktv, const int4* __restrict__ meta,
    const int* __restrict__ node_type,
    const float* __restrict__ rel_pri, const float* __restrict__ rel_att,
    const float* __restrict__ mtg, const int* __restrict__ row_start,
    float* __restrict__ h_out) {
    __shared__ float At[8192];        // At[l*512 + (r*8+h)*16 + k]  (32768 B)
    __shared__ float scr[8][1344];    // per wave: qA0[544] qA1[544] pl[256]
    // total 75776 B -> 2 blocks/CU, 16 waves/CU

    int tid = threadIdx.x;
    // ---- stage rel_att (once per block; 512 threads x 4 passes) ----
    for (int g0 = tid * 4; g0 < 8192; g0 += 2048) {
        float4 a = *(const float4*)(rel_att + g0);
        int la = g0 & 15, ka = (g0 >> 4) & 15, rh = g0 >> 8;
        At[(la + 0) * 512 + rh * 16 + ka] = a.x;
        At[(la + 1) * 512 + rh * 16 + ka] = a.y;
        At[(la + 2) * 512 + rh * 16 + ka] = a.z;
        At[(la + 3) * 512 + rh * 16 + ka] = a.w;
    }
    __syncthreads();   // the ONLY barrier; everything below is wave-independent

    int w = tid >> 6;
    int lane = tid & 63;
    float* qA0 = scr[w];          // [h*68 + r*17 + k]
    float* qA1 = scr[w] + 544;
    float* pl  = scr[w] + 1088;   // 256 floats: p for 32 edges x 8 heads

    int hE = lane >> 4;               // head slice 0..3 (even-u), +4 for odd-u
    int j  = lane >> 3, h = lane & 7; // score mapping: lane = j*8 + h
    int h2 = lane >> 3, d0 = lane * 2;// aggr mapping: head h2, dims d0,d0+1
    int cp = (lane & 7) * 2;          // epilogue col pair within head
    int kk = lane & 15;               // prologue k index
    int nbase = blockIdx.x * 64 + w * 8;

    for (int pr = 0; pr < 4; ++pr) {
        int n0 = nbase + 2 * pr;
        if (n0 >= NN) break;          // NN even: n0 < NN implies n0+1 < NN

        // q slices for BOTH nodes into registers
        const float4* q0p  = (const float4*)(Qn + (size_t)n0 * 128 + hE * 16);
        const float4* q0p2 = (const float4*)(Qn + (size_t)n0 * 128 + 64 + hE * 16);
        const float4* q1p  = (const float4*)(Qn + (size_t)(n0 + 1) * 128 + hE * 16);
        const float4* q1p2 = (const float4*)(Qn + (size_t)(n0 + 1) * 128 + 64 + hE * 16);
        float4 aE0 = q0p[0],  aE1 = q0p[1],  aE2 = q0p[2],  aE3 = q0p[3];
        float4 aO0 = q0p2[0], aO1 = q0p2[1], aO2 = q0p2[2], aO3 = q0p2[3];
        float4 bE0 = q1p[0],  bE1 = q1p[1],  bE2 = q1p[2],  bE3 = q1p[3];
        float4 bO0 = q1p2[0], bO1 = q1p2[1], bO2 = q1p2[2], bO3 = q1p2[3];

        int eb0 = row_start[n0];
        int eb1 = row_start[n0 + 1];
        int eb2 = row_start[n0 + 2];

        // ---- pair-prologue: shared At reads feed two dot products ----
        #pragma unroll
        for (int u = 0; u < 8; ++u) {
            int f = u * 64 + lane;    // f = (r*8+h)*16 + k; h=(u&1)*4+hE, r=u>>1
            const float* a = &At[f];
            float t0 = a[0*512],  t1 = a[1*512],  t2 = a[2*512],  t3 = a[3*512];
            float t4 = a[4*512],  t5 = a[5*512],  t6 = a[6*512],  t7 = a[7*512];
            float t8 = a[8*512],  t9 = a[9*512],  t10 = a[10*512], t11 = a[11*512];
            float t12 = a[12*512], t13 = a[13*512], t14 = a[14*512], t15 = a[15*512];
            float4 qa0 = (u & 1) ? aO0 : aE0, qa1 = (u & 1) ? aO1 : aE1;
            float4 qa2 = (u & 1) ? aO2 : aE2, qa3 = (u & 1) ? aO3 : aE3;
            float4 qb0 = (u & 1) ? bO0 : bE0, qb1 = (u & 1) ? bO1 : bE1;
            float4 qb2 = (u & 1) ? bO2 : bE2, qb3 = (u & 1) ? bO3 : bE3;
            float v0 = t0*qa0.x + t1*qa0.y + t2*qa0.z + t3*qa0.w
                     + t4*qa1.x + t5*qa1.y + t6*qa1.z + t7*qa1.w
                     + t8*qa2.x + t9*qa2.y + t10*qa2.z + t11*qa2.w
                     + t12*qa3.x + t13*qa3.y + t14*qa3.z + t15*qa3.w;
            float v1 = t0*qb0.x + t1*qb0.y + t2*qb0.z + t3*qb0.w
                     + t4*qb1.x + t5*qb1.y + t6*qb1.z + t7*qb1.w
                     + t8*qb2.x + t9*qb2.y + t10*qb2.z + t11*qb2.w
                     + t12*qb3.x + t13*qb3.y + t14*qb3.z + t15*qb3.w;
            int hh = (u & 1) * 4 + hE;
            int rr = u >> 1;
            int idx = hh * 68 + rr * 17 + kk;
            qA0[idx] = v0;
            qA1[idx] = v1;
        }

        // ---- process the two nodes sequentially (R7/R8-proven body) ----
        for (int s = 0; s < 2; ++s) {
            int n = n0 + s;
            int e_beg = s ? eb1 : eb0;
            int e_end = s ? eb2 : eb1;
            const float* qA = s ? qA1 : qA0;
            int tt = node_type[n];

            int4 mm = make_int4(0, 0, 0, 0);
            if (lane < 32 && e_beg + lane < e_end) mm = meta[e_beg + lane];

            float ls = 0.f;
            float2 a0v = {0.f,0.f}, a1v = {0.f,0.f}, a2v = {0.f,0.f}, a3v = {0.f,0.f};
            int rmask = 0;

            for (int cb = e_beg; cb < e_end; cb += 32) {
                if (cb > e_beg) {
                    mm = make_int4(0, 0, 0, 0);
                    if (lane < 32 && cb + lane < e_end) mm = meta[cb + lane];
                }
                int cdeg = min(32, e_end - cb);
                // ---- score: 8 edges x 8 heads per pass; p -> wave-private LDS ----
                int nss = (cdeg + 7) >> 3;
                for (int ss = 0; ss < nss; ++ss) {
                    int sl = ss * 8 + j;
                    int ei = cb + sl;
                    bool valid = ei < e_end;
                    int mxs = __shfl(mm.x, sl, 64);
                    int mys = __shfl(mm.y, sl, 64);
                    int r = mys & 3, st = (mys >> 2) & 3, tb = mys >> 6;
                    const float4* kp = (const float4*)(KV + (size_t)mxs * 256 + h * 16);
                    const float4* tp = (const float4*)(ktv + (size_t)tb * 256 + h * 16);
                    float4 k0 = kp[0], k1 = kp[1], k2 = kp[2], k3 = kp[3];
                    float4 t0 = tp[0], t1 = tp[1], t2 = tp[2], t3 = tp[3];
                    const float* qa = qA + h * 68 + r * 17;   // conflict-free banks
                    float sv = (k0.x + t0.x) * qa[0]  + (k0.y + t0.y) * qa[1]
                             + (k0.z + t0.z) * qa[2]  + (k0.w + t0.w) * qa[3]
                             + (k1.x + t1.x) * qa[4]  + (k1.y + t1.y) * qa[5]
                             + (k1.z + t1.z) * qa[6]  + (k1.w + t1.w) * qa[7]
                             + (k2.x + t2.x) * qa[8]  + (k2.y + t2.y) * qa[9]
                             + (k2.z + t2.z) * qa[10] + (k2.w + t2.w) * qa[11]
                             + (k3.x + t3.x) * qa[12] + (k3.y + t3.y) * qa[13]
                             + (k3.z + t3.z) * qa[14] + (k3.w + t3.w) * qa[15];
                    float pri = rel_pri[((tt * 4 + r) * 3 + st) * 8 + h];
                    float p = valid ? __expf(sv * pri * 0.25f) : 0.f;
                    pl[ss * 64 + lane] = p;   // pl[sl*8 + h]: conflict-free
                    ls += p;
                }
                // ---- aggregation: serial over chunk edges, v gathered coalesced ----
                int mx = mm.x, my = mm.y;
                #pragma unroll 4
                for (int i = 0; i < cdeg; ++i) {
                    int src  = __shfl(mx, i, 64);
                    int code = __shfl(my, i, 64);
                    int r = code & 3;
                    float pv = pl[i * 8 + h2];   // broadcast within 8-lane groups
                    float2 v1 = *(const float2*)(KV + (size_t)src * 256 + 128 + d0);
                    float2 v2 = *(const float2*)(ktv + (size_t)(code >> 6) * 256 + 128 + d0);
                    float vx = pv * (v1.x + v2.x);
                    float vy = pv * (v1.y + v2.y);
                    rmask |= (1 << r);
                    switch (r) {
                        case 0: a0v.x += vx; a0v.y += vy; break;
                        case 1: a1v.x += vx; a1v.y += vy; break;
                        case 2: a2v.x += vx; a2v.y += vy; break;
                        default: a3v.x += vx; a3v.y += vy; break;
                    }
                }
            }

            // ---- softmax denominator ----
            ls += __shfl_xor(ls, 8, 64);
            ls += __shfl_xor(ls, 16, 64);
            ls += __shfl_xor(ls, 32, 64);
            float lst = __shfl(ls, h2, 64);        // lane h2 holds total for head h2
            float iv = (lst > 0.f) ? (1.f / lst) : 0.f;

            // ---- epilogue: shfl acc + Mtg global reads (L1-hot 32KB table) ----
            float o0 = 0.f, o1 = 0.f;
            #pragma unroll
            for (int r = 0; r < 4; ++r) {
                if (rmask & (1 << r)) {
                    float sx[16];
                    #pragma unroll
                    for (int m = 0; m < 8; ++m) {
                        float ax, ay;
                        if (r == 0)      { ax = __shfl(a0v.x, h2 * 8 + m, 64); ay = __shfl(a0v.y, h2 * 8 + m, 64); }
                        else if (r == 1) { ax = __shfl(a1v.x, h2 * 8 + m, 64); ay = __shfl(a1v.y, h2 * 8 + m, 64); }
                        else if (r == 2) { ax = __shfl(a2v.x, h2 * 8 + m, 64); ay = __shfl(a2v.y, h2 * 8 + m, 64); }
                        else             { ax = __shfl(a3v.x, h2 * 8 + m, 64); ay = __shfl(a3v.y, h2 * 8 + m, 64); }
                        sx[2 * m] = ax; sx[2 * m + 1] = ay;
                    }
                    // Mtg[((r*8+h2)*16 + c)*16 + i]: 16 i's contiguous per (c)
                    const float* Mb = mtg + (size_t)(((r * 8 + h2) * 16 + cp) * 16);
                    const float4* M0 = (const float4*)Mb;
                    float4 x0 = M0[0], x1 = M0[1], x2 = M0[2], x3 = M0[3];
                    o0 += sx[0]*x0.x + sx[1]*x0.y + sx[2]*x0.z + sx[3]*x0.w
                        + sx[4]*x1.x + sx[5]*x1.y + sx[6]*x1.z + sx[7]*x1.w
                        + sx[8]*x2.x + sx[9]*x2.y + sx[10]*x2.z + sx[11]*x2.w
                        + sx[12]*x3.x + sx[13]*x3.y + sx[14]*x3.z + sx[15]*x3.w;
                    const float4* M1 = (const float4*)(Mb + 16);
                    float4 y0 = M1[0], y1 = M1[1], y2 = M1[2], y3 = M1[3];
                    o1 += sx[0]*y0.x + sx[1]*y0.y + sx[2]*y0.z + sx[3]*y0.w
                        + sx[4]*y1.x + sx[5]*y1.y + sx[6]*y1.z + sx[7]*y1.w
                        + sx[8]*y2.x + sx[9]*y2.y + sx[10]*y2.z + sx[11]*y2.w
                        + sx[12]*y3.x + sx[13]*y3.y + sx[14]*y3.z + sx[15]*y3.w;
                }
            }
            o0 *= iv; o1 *= iv;
            // exact gelu
            o0 = 0.5f * o0 * (1.f + erff(o0 * 0.7071067811865475f));
            o1 = 0.5f * o1 * (1.f + erff(o1 * 0.7071067811865475f));
            *(float2*)(h_out + (size_t)n * 128 + d0) = make_float2(o0, o1);
        }
    }
}

// ---------------- launcher ----------------
extern "C" void kernel_launch(void* const* d_in, const int* in_sizes, int n_in,
                              void* d_out, int out_size, void* d_ws, size_t ws_size,
                              hipStream_t stream) {
    const float* node_feature = (const float*)d_in[0];
    const int*   node_type    = (const int*)d_in[1];
    const int*   edge_index   = (const int*)d_in[2];   // [2,E]: src then tgt
    const int*   edge_type    = (const int*)d_in[3];
    const int*   edge_time    = (const int*)d_in[4];
    const float* adapt_w      = (const float*)d_in[5];
    const float* adapt_b      = (const float*)d_in[6];
    const float* Wk           = (const float*)d_in[7];
    const float* bk           = (const float*)d_in[8];
    const float* Wq           = (const float*)d_in[9];
    const float* bq           = (const float*)d_in[10];
    const float* Wv           = (const float*)d_in[11];
    const float* bv           = (const float*)d_in[12];
    const float* Wa           = (const float*)d_in[13];
    const float* ba           = (const float*)d_in[14];
    const float* rel_pri      = (const float*)d_in[15];
    const float* rel_att      = (const float*)d_in[16];
    const float* rel_msg      = (const float*)d_in[17];
    const float* skip         = (const float*)d_in[18];
    const float* rte_w        = (const float*)d_in[19];
    const float* rte_b        = (const float*)d_in[20];
    float* out = (float*)d_out;

    const size_t ND = (size_t)NN * 128;
    float* Qn     = (float*)d_ws;            // N*128 (reused as h buffer)
    float* KV     = Qn + ND;                 // N*256 (k|v per row)
    float* rtab   = KV + 2 * ND;             // 240*256
    float* rproj  = rtab + 240 * 256;        // 240*128
    float* ktv    = rproj + 240 * 128;       // 720*256 (k|v per row)
    int*   cnt    = (int*)(ktv + 720 * 256);
    int*   fill   = cnt + NN;
    int*   row_st = fill + NN;               // NN+1 (+pad)
    int*   order  = row_st + NN + 4;         // NN
    int*   tcnt   = order + NN;              // 3 (+pad)
    int*   fill3  = tcnt + 4;                // 3 (+pad)
    int4*  meta   = (int4*)(fill3 + 4);      // EE int4
    float* mtg    = (float*)(meta + EE);     // 8192 (transposed rel_msg, per layer)
    // total ~165 MB

    const int* esrc = edge_index;
    const int* etgt = edge_index + EE;

    hipMemsetAsync(cnt, 0, 2 * NN * sizeof(int), stream);
    hipMemsetAsync(tcnt, 0, 8 * sizeof(int), stream);
    rte_tab_kernel<<<240, 256, 0, stream>>>(rtab);
    hist_kernel<<<(EE + 255) / 256, 256, 0, stream>>>(etgt, cnt);
    scan_kernel<<<1, 1024, 0, stream>>>(cnt, row_st);
    scatter_meta_kernel<<<(EE + 255) / 256, 256, 0, stream>>>(esrc, etgt, edge_type,
                                                              edge_time, node_type,
                                                              row_st, fill, meta);
    node_hist_kernel<<<(NN + 255) / 256, 256, 0, stream>>>(node_type, tcnt);
    node_scatter_kernel<<<(NN + 255) / 256, 256, 0, stream>>>(node_type, tcnt, fill3, order);

    // input adaptation: x = tanh(typed_linear(node_feature))
    typed_lin_kernel<0><<<NN / 32, 256, 0, stream>>>(node_feature, node_type, order,
                                                     adapt_w, adapt_b, nullptr, out);

    for (int l = 0; l < 2; ++l) {
        const float* Wk_l = Wk + l * 49152;  const float* bk_l = bk + l * 384;
        const float* Wq_l = Wq + l * 49152;  const float* bq_l = bq + l * 384;
        const float* Wv_l = Wv + l * 49152;  const float* bv_l = bv + l * 384;
        const float* Wa_l = Wa + l * 49152;  const float* ba_l = ba + l * 384;
        const float* pri_l = rel_pri + l * 288;
        const float* att_l = rel_att + l * 8192;
        const float* msg_l = rel_msg + l * 8192;
        const float* skip_l = skip + l * 3;
        const float* rte_w_l = rte_w + l * 32768;
        const float* rte_b_l = rte_b + l * 128;

        rte_proj_kernel<<<240, 128, 0, stream>>>(rtab, rte_w_l, rte_b_l, rproj);
        ktv_kernel<<<720, 128, 0, stream>>>(rproj, Wk_l, Wv_l, ktv);
        msg_t_kernel<<<32, 256, 0, stream>>>(msg_l, mtg);
        qkv_kernel<<<NN / 32, 256, 0, stream>>>(out, node_type, order, Wq_l, bq_l,
                                                Wk_l, bk_l, Wv_l, bv_l, Qn, KV);
        edge_kernel<<<(NN + 63) / 64, 512, 0, stream>>>(Qn, KV, ktv, meta, node_type,
                                                        pri_l, att_l, mtg, row_st,
                                                        Qn /* h overwrites Qn: safe */);
        typed_lin_kernel<1><<<NN / 32, 256, 0, stream>>>(Qn, node_type, order, Wa_l, ba_l,
                                                         skip_l, out);
    }
}

// Round 10
// 1573.810 us; speedup vs baseline: 1.2195x; 1.2195x over previous
//
#include <hip/hip_runtime.h>
#include <math.h>

#define NN 100000
#define EE 500000

// ---------------- RTE sinusoid table [240, 256] ----------------
__global__ void rte_tab_kernel(float* __restrict__ tab) {
    int p = blockIdx.x;      // 0..239
    int j = threadIdx.x;     // 0..255
    int m = j >> 1;
    // replicate fp32 overflow: 10000^(2m) -> inf for 2m >= 10 in fp32
    float pf = (float)pow(10000.0, (double)(2 * m));
    float dv = 1.0f / (pf / 128.0f / 2.0f);
    float ang = (float)p * dv;
    const float s = 0.08838834764831845f; // 1/sqrt(128)
    float v = (j & 1) ? (cosf(ang) * s) : (sinf(ang) * s);
    tab[p * 256 + j] = v;
}

// ---------------- rte_proj[p,c] = rte_tab[p,:] @ rte_w + rte_b ----------------
__global__ void rte_proj_kernel(const float* __restrict__ tab,
                                const float* __restrict__ rte_w,
                                const float* __restrict__ rte_b,
                                float* __restrict__ proj) {
    __shared__ float row[256];
    int p = blockIdx.x;           // 240
    int c = threadIdx.x;          // 128
    for (int i = threadIdx.x; i < 256; i += 128) row[i] = tab[p * 256 + i];
    __syncthreads();
    float acc = rte_b[c];
    #pragma unroll 8
    for (int q = 0; q < 256; ++q) acc += row[q] * rte_w[q * 128 + c];
    proj[p * 128 + c] = acc;
}

// ---------------- ktv[b][0:128]=proj@Wk[t], ktv[b][128:256]=proj@Wv[t] ----------------
__global__ void ktv_kernel(const float* __restrict__ proj,
                           const float* __restrict__ Wk,
                           const float* __restrict__ Wv,
                           float* __restrict__ ktv) {
    __shared__ float row[128];
    int b = blockIdx.x;           // 720 = t*240 + p
    int t = b / 240, p = b % 240;
    int c = threadIdx.x;          // 128
    row[c] = proj[p * 128 + c];
    __syncthreads();
    const float* wk = Wk + t * 16384 + c;
    const float* wv = Wv + t * 16384 + c;
    float ak = 0.f, av = 0.f;
    #pragma unroll 8
    for (int q = 0; q < 128; ++q) {
        float rv = row[q];
        ak += rv * wk[q * 128];
        av += rv * wv[q * 128];
    }
    ktv[(size_t)b * 256 + c] = ak;
    ktv[(size_t)b * 256 + 128 + c] = av;
}

// ---------------- CSR build (edges grouped by target) ----------------
__global__ void hist_kernel(const int* __restrict__ tgt, int* __restrict__ cnt) {
    int e = blockIdx.x * blockDim.x + threadIdx.x;
    if (e < EE) atomicAdd(&cnt[tgt[e]], 1);
}

__global__ void scan_kernel(const int* __restrict__ cnt, int* __restrict__ row_start) {
    __shared__ int sdata[1024];
    __shared__ int s_running;
    if (threadIdx.x == 0) s_running = 0;
    __syncthreads();
    for (int base = 0; base < NN; base += 1024) {
        int i = base + (int)threadIdx.x;
        int v = (i < NN) ? cnt[i] : 0;
        sdata[threadIdx.x] = v;
        __syncthreads();
        int acc = v;
        for (int off = 1; off < 1024; off <<= 1) {
            int t = (threadIdx.x >= (unsigned)off) ? sdata[threadIdx.x - off] : 0;
            __syncthreads();
            acc += t;
            sdata[threadIdx.x] = acc;
            __syncthreads();
        }
        int run = s_running;
        if (i < NN) row_start[i] = run + acc - v;   // exclusive
        __syncthreads();
        if (threadIdx.x == 1023) s_running = run + sdata[1023];
        __syncthreads();
    }
    if (threadIdx.x == 0) row_start[NN] = s_running;
}

// scatter + meta fused: meta[pos] = {src, (tb<<6)|(tt<<4)|(st<<2)|r, tgt, 0}
__global__ void scatter_meta_kernel(const int* __restrict__ esrc,
                                    const int* __restrict__ etgt,
                                    const int* __restrict__ etype,
                                    const int* __restrict__ etime,
                                    const int* __restrict__ node_type,
                                    const int* __restrict__ row_start,
                                    int* __restrict__ fill,
                                    int4* __restrict__ meta) {
    int e = blockIdx.x * blockDim.x + threadIdx.x;
    if (e < EE) {
        int tgt = etgt[e];
        int src = esrc[e];
        int r = etype[e];
        int tm = etime[e];
        int st = node_type[src];
        int tt = node_type[tgt];
        int tb = st * 240 + tm;
        int pos = row_start[tgt] + atomicAdd(&fill[tgt], 1);
        meta[pos] = make_int4(src, (tb << 6) | (tt << 4) | (st << 2) | r, tgt, 0);
    }
}

// ---------------- node counting sort by type (3 bins) ----------------
__global__ void node_hist_kernel(const int* __restrict__ nt, int* __restrict__ tcnt) {
    __shared__ int lc[3];
    if (threadIdx.x < 3) lc[threadIdx.x] = 0;
    __syncthreads();
    int i = blockIdx.x * blockDim.x + threadIdx.x;
    if (i < NN) atomicAdd(&lc[nt[i]], 1);
    __syncthreads();
    if (threadIdx.x < 3) atomicAdd(&tcnt[threadIdx.x], lc[threadIdx.x]);
}

__global__ void node_scatter_kernel(const int* __restrict__ nt,
                                    const int* __restrict__ tcnt,
                                    int* __restrict__ fill3,
                                    int* __restrict__ order) {
    __shared__ int lc[3], lbase[3], lfill[3];
    if (threadIdx.x < 3) { lc[threadIdx.x] = 0; lfill[threadIdx.x] = 0; }
    __syncthreads();
    int i = blockIdx.x * blockDim.x + threadIdx.x;
    int t = -1;
    if (i < NN) { t = nt[i]; atomicAdd(&lc[t], 1); }
    __syncthreads();
    if (threadIdx.x < 3) lbase[threadIdx.x] = atomicAdd(&fill3[threadIdx.x], lc[threadIdx.x]);
    __syncthreads();
    if (i < NN) {
        int rank = atomicAdd(&lfill[t], 1);
        int tb = (t == 0) ? 0 : ((t == 1) ? tcnt[0] : tcnt[0] + tcnt[1]);
        order[tb + lbase[t] + rank] = i;
    }
}

// ---------------- typed linear over type-sorted nodes ----------------
template <int MODE>
__global__ __launch_bounds__(256) void typed_lin_kernel(
    const float* __restrict__ in, const int* __restrict__ nt,
    const int* __restrict__ order,
    const float* __restrict__ W, const float* __restrict__ b,
    const float* __restrict__ skip, float* __restrict__ out) {
    __shared__ float xs[32][128];
    __shared__ int rows[32];
    __shared__ int sty[32];
    int nb = blockIdx.x * 32;
    if (threadIdx.x < 32) {
        int r = order[nb + threadIdx.x];
        rows[threadIdx.x] = r;
        sty[threadIdx.x] = nt[r];
    }
    __syncthreads();
    for (int i = threadIdx.x; i < 1024; i += 256) {
        int nl = i >> 5, e4 = i & 31;
        *(float4*)&xs[nl][e4 * 4] = *(const float4*)(in + (size_t)rows[nl] * 128 + e4 * 4);
    }
    __syncthreads();
    int col = threadIdx.x & 127;
    int ng  = (threadIdx.x >> 7) * 16;
    int t0 = sty[ng];
    bool uni = true;
    #pragma unroll
    for (int ii = 1; ii < 16; ++ii) uni &= (sty[ng + ii] == t0);
    if (uni) {
        const float* w = W + t0 * 16384 + col;
        float bv = b[t0 * 128 + col];
        float alpha = (MODE == 1) ? (1.f / (1.f + __expf(-skip[t0]))) : 0.f;
        float acc[16];
        #pragma unroll
        for (int ii = 0; ii < 16; ++ii) acc[ii] = bv;
        for (int k0 = 0; k0 < 128; k0 += 4) {
            float w0 = w[(k0 + 0) * 128];
            float w1 = w[(k0 + 1) * 128];
            float w2 = w[(k0 + 2) * 128];
            float w3 = w[(k0 + 3) * 128];
            #pragma unroll
            for (int ii = 0; ii < 16; ++ii) {
                float4 xv = *(const float4*)&xs[ng + ii][k0];
                acc[ii] += xv.x * w0 + xv.y * w1 + xv.z * w2 + xv.w * w3;
            }
        }
        #pragma unroll
        for (int ii = 0; ii < 16; ++ii) {
            size_t gi = (size_t)rows[ng + ii] * 128 + col;
            if (MODE == 0) out[gi] = tanhf(acc[ii]);
            else           out[gi] = alpha * acc[ii] + (1.f - alpha) * out[gi];
        }
    } else {
        for (int ii = 0; ii < 16; ++ii) {
            int nl = ng + ii;
            int t = sty[nl];
            const float* w = W + t * 16384 + col;
            float acc = b[t * 128 + col];
            #pragma unroll 8
            for (int k = 0; k < 128; ++k) acc += xs[nl][k] * w[k * 128];
            size_t gi = (size_t)rows[nl] * 128 + col;
            if (MODE == 0) out[gi] = tanhf(acc);
            else {
                float alpha = 1.f / (1.f + __expf(-skip[t]));
                out[gi] = alpha * acc + (1.f - alpha) * out[gi];
            }
        }
    }
}

// ---------------- fused Q/K/V typed projections; K/V interleaved per row ----------------
__global__ __launch_bounds__(256) void qkv_kernel(
    const float* __restrict__ x, const int* __restrict__ nt,
    const int* __restrict__ order,
    const float* __restrict__ Wq, const float* __restrict__ bq,
    const float* __restrict__ Wk, const float* __restrict__ bk,
    const float* __restrict__ Wv, const float* __restrict__ bv,
    float* __restrict__ Qn, float* __restrict__ KV) {
    __shared__ float xs[32][128];
    __shared__ int rows[32];
    __shared__ int sty[32];
    int nb = blockIdx.x * 32;
    if (threadIdx.x < 32) {
        int r = order[nb + threadIdx.x];
        rows[threadIdx.x] = r;
        sty[threadIdx.x] = nt[r];
    }
    __syncthreads();
    for (int i = threadIdx.x; i < 1024; i += 256) {
        int nl = i >> 5, e4 = i & 31;
        *(float4*)&xs[nl][e4 * 4] = *(const float4*)(x + (size_t)rows[nl] * 128 + e4 * 4);
    }
    __syncthreads();
    int col = threadIdx.x & 127;
    int ng  = (threadIdx.x >> 7) * 16;
    int t0 = sty[ng];
    bool uni = true;
    #pragma unroll
    for (int ii = 1; ii < 16; ++ii) uni &= (sty[ng + ii] == t0);
    if (uni) {
        const float* wq = Wq + t0 * 16384 + col;
        const float* wk = Wk + t0 * 16384 + col;
        const float* wv = Wv + t0 * 16384 + col;
        float bqv = bq[t0 * 128 + col];
        float bkv = bk[t0 * 128 + col];
        float bvv = bv[t0 * 128 + col];
        float aq[16], ak[16], av[16];
        #pragma unroll
        for (int ii = 0; ii < 16; ++ii) { aq[ii] = bqv; ak[ii] = bkv; av[ii] = bvv; }
        for (int k0 = 0; k0 < 128; k0 += 4) {
            float q0 = wq[(k0 + 0) * 128], q1 = wq[(k0 + 1) * 128];
            float q2 = wq[(k0 + 2) * 128], q3 = wq[(k0 + 3) * 128];
            float k0w = wk[(k0 + 0) * 128], k1w = wk[(k0 + 1) * 128];
            float k2w = wk[(k0 + 2) * 128], k3w = wk[(k0 + 3) * 128];
            float v0 = wv[(k0 + 0) * 128], v1 = wv[(k0 + 1) * 128];
            float v2 = wv[(k0 + 2) * 128], v3 = wv[(k0 + 3) * 128];
            #pragma unroll
            for (int ii = 0; ii < 16; ++ii) {
                float4 xv = *(const float4*)&xs[ng + ii][k0];
                aq[ii] += xv.x * q0 + xv.y * q1 + xv.z * q2 + xv.w * q3;
                ak[ii] += xv.x * k0w + xv.y * k1w + xv.z * k2w + xv.w * k3w;
                av[ii] += xv.x * v0 + xv.y * v1 + xv.z * v2 + xv.w * v3;
            }
        }
        #pragma unroll
        for (int ii = 0; ii < 16; ++ii) {
            size_t row = (size_t)rows[ng + ii];
            Qn[row * 128 + col] = aq[ii];
            KV[row * 256 + col] = ak[ii];
            KV[row * 256 + 128 + col] = av[ii];
        }
    } else {
        for (int ii = 0; ii < 16; ++ii) {
            int nl = ng + ii;
            int t = sty[nl];
            const float* wq = Wq + t * 16384 + col;
            const float* wk = Wk + t * 16384 + col;
            const float* wv = Wv + t * 16384 + col;
            float aq = bq[t * 128 + col];
            float ak = bk[t * 128 + col];
            float av = bv[t * 128 + col];
            #pragma unroll 4
            for (int k = 0; k < 128; ++k) {
                float xv = xs[nl][k];
                aq += xv * wq[k * 128];
                ak += xv * wk[k * 128];
                av += xv * wv[k * 128];
            }
            size_t row = (size_t)rows[nl];
            Qn[row * 128 + col] = aq;
            KV[row * 256 + col] = ak;
            KV[row * 256 + 128 + col] = av;
        }
    }
}

// ---------------- fused score + softmax + aggregation, LDS-staged tables ----------------
// R10 = R8 body at 1024 threads (16 waves/CU -- the occupancy R4 demonstrated
// at 41.7% -- WITHOUT R4's fatal __launch_bounds__(1024,4) VGPR-64 clamp; no
// min-waves arg leaves compiler at its natural ~120 VGPR = 4 waves/SIMD).
// R9 lesson: moving Mt to global dropped conflicts 10x but ADDED latency
// (344->460) and never raised occupancy -- conflicts are benign; Mt back in LDS.
// To fit LDS at 16 waves: edge chunk 32 -> 16 (pl 256 -> 128 floats):
//   At 32768 + Mt 41344 + scr 16*1216*4 = 151936 B <= 160 KB, 1 block/CU.
// Each wave: 2 pairs of nodes (4 nodes), pair-prologue shares At reads.
// Mt layout addr(r,h,c,i) = r*2584 + 324h + 20c + i (R7-proven, injective).
__global__ __launch_bounds__(1024) void edge_kernel(
    const float* __restrict__ Qn, const float* __restrict__ KV,
    const float* __restrict__ ktv, const int4* __restrict__ meta,
    const int* __restrict__ node_type,
    const float* __restrict__ rel_pri, const float* __restrict__ rel_att,
    const float* __restrict__ rel_msg, const int* __restrict__ row_start,
    float* __restrict__ h_out) {
    __shared__ float At[8192];        // At[l*512 + (r*8+h)*16 + k]      (32768 B)
    __shared__ float Mt[10336];       // Mt[r*2584 + 324h + 20c + i]     (41344 B)
    __shared__ float scr[16][1216];   // per wave: qA0[544] qA1[544] pl[128]

    int tid = threadIdx.x;
    // ---- stage tables (once per block; 1024 threads x 2 passes) ----
    for (int g0 = tid * 4; g0 < 8192; g0 += 4096) {
        float4 a = *(const float4*)(rel_att + g0);
        int la = g0 & 15, ka = (g0 >> 4) & 15, rh = g0 >> 8;
        At[(la + 0) * 512 + rh * 16 + ka] = a.x;
        At[(la + 1) * 512 + rh * 16 + ka] = a.y;
        At[(la + 2) * 512 + rh * 16 + ka] = a.z;
        At[(la + 3) * 512 + rh * 16 + ka] = a.w;
        float4 m = *(const float4*)(rel_msg + g0);
        int cm = g0 & 15, im = (g0 >> 4) & 15, hm = (g0 >> 8) & 7, rm = g0 >> 11;
        int rb = rm * 2584 + 324 * hm + 20 * cm + im;
        Mt[rb]      = m.x;
        Mt[rb + 20] = m.y;
        Mt[rb + 40] = m.z;
        Mt[rb + 60] = m.w;
    }
    __syncthreads();   // the ONLY barrier; everything below is wave-independent

    int w = tid >> 6;             // 0..15
    int lane = tid & 63;
    float* qA0 = scr[w];          // [h*68 + r*17 + k]
    float* qA1 = scr[w] + 544;
    float* pl  = scr[w] + 1088;   // 128 floats: p for 16 edges x 8 heads

    int hE = lane >> 4;               // head slice 0..3 (even-u), +4 for odd-u
    int j  = lane >> 3, h = lane & 7; // score mapping: lane = j*8 + h
    int h2 = lane >> 3, d0 = lane * 2;// aggr mapping: head h2, dims d0,d0+1
    int cp = (lane & 7) * 2;          // epilogue col pair within head
    int kk = lane & 15;               // prologue k index
    int nbase = blockIdx.x * 64 + w * 4;

    for (int pr = 0; pr < 2; ++pr) {
        int n0 = nbase + 2 * pr;
        if (n0 >= NN) break;          // NN even: n0 < NN implies n0+1 < NN

        // q slices for BOTH nodes into registers
        const float4* q0p  = (const float4*)(Qn + (size_t)n0 * 128 + hE * 16);
        const float4* q0p2 = (const float4*)(Qn + (size_t)n0 * 128 + 64 + hE * 16);
        const float4* q1p  = (const float4*)(Qn + (size_t)(n0 + 1) * 128 + hE * 16);
        const float4* q1p2 = (const float4*)(Qn + (size_t)(n0 + 1) * 128 + 64 + hE * 16);
        float4 aE0 = q0p[0],  aE1 = q0p[1],  aE2 = q0p[2],  aE3 = q0p[3];
        float4 aO0 = q0p2[0], aO1 = q0p2[1], aO2 = q0p2[2], aO3 = q0p2[3];
        float4 bE0 = q1p[0],  bE1 = q1p[1],  bE2 = q1p[2],  bE3 = q1p[3];
        float4 bO0 = q1p2[0], bO1 = q1p2[1], bO2 = q1p2[2], bO3 = q1p2[3];

        int eb0 = row_start[n0];
        int eb1 = row_start[n0 + 1];
        int eb2 = row_start[n0 + 2];

        // ---- pair-prologue: shared At reads feed two dot products ----
        #pragma unroll
        for (int u = 0; u < 8; ++u) {
            int f = u * 64 + lane;    // f = (r*8+h)*16 + k; h=(u&1)*4+hE, r=u>>1
            const float* a = &At[f];
            float t0 = a[0*512],  t1 = a[1*512],  t2 = a[2*512],  t3 = a[3*512];
            float t4 = a[4*512],  t5 = a[5*512],  t6 = a[6*512],  t7 = a[7*512];
            float t8 = a[8*512],  t9 = a[9*512],  t10 = a[10*512], t11 = a[11*512];
            float t12 = a[12*512], t13 = a[13*512], t14 = a[14*512], t15 = a[15*512];
            float4 qa0 = (u & 1) ? aO0 : aE0, qa1 = (u & 1) ? aO1 : aE1;
            float4 qa2 = (u & 1) ? aO2 : aE2, qa3 = (u & 1) ? aO3 : aE3;
            float4 qb0 = (u & 1) ? bO0 : bE0, qb1 = (u & 1) ? bO1 : bE1;
            float4 qb2 = (u & 1) ? bO2 : bE2, qb3 = (u & 1) ? bO3 : bE3;
            float v0 = t0*qa0.x + t1*qa0.y + t2*qa0.z + t3*qa0.w
                     + t4*qa1.x + t5*qa1.y + t6*qa1.z + t7*qa1.w
                     + t8*qa2.x + t9*qa2.y + t10*qa2.z + t11*qa2.w
                     + t12*qa3.x + t13*qa3.y + t14*qa3.z + t15*qa3.w;
            float v1 = t0*qb0.x + t1*qb0.y + t2*qb0.z + t3*qb0.w
                     + t4*qb1.x + t5*qb1.y + t6*qb1.z + t7*qb1.w
                     + t8*qb2.x + t9*qb2.y + t10*qb2.z + t11*qb2.w
                     + t12*qb3.x + t13*qb3.y + t14*qb3.z + t15*qb3.w;
            int hh = (u & 1) * 4 + hE;
            int rr = u >> 1;
            int idx = hh * 68 + rr * 17 + kk;
            qA0[idx] = v0;
            qA1[idx] = v1;
        }

        // ---- process the two nodes sequentially (R7/R8-proven body) ----
        for (int s = 0; s < 2; ++s) {
            int n = n0 + s;
            int e_beg = s ? eb1 : eb0;
            int e_end = s ? eb2 : eb1;
            const float* qA = s ? qA1 : qA0;
            int tt = node_type[n];

            int4 mm = make_int4(0, 0, 0, 0);
            if (lane < 16 && e_beg + lane < e_end) mm = meta[e_beg + lane];

            float ls = 0.f;
            float2 a0v = {0.f,0.f}, a1v = {0.f,0.f}, a2v = {0.f,0.f}, a3v = {0.f,0.f};
            int rmask = 0;

            for (int cb = e_beg; cb < e_end; cb += 16) {
                if (cb > e_beg) {
                    mm = make_int4(0, 0, 0, 0);
                    if (lane < 16 && cb + lane < e_end) mm = meta[cb + lane];
                }
                int cdeg = min(16, e_end - cb);
                // ---- score: 8 edges x 8 heads per pass; p -> wave-private LDS ----
                int nss = (cdeg + 7) >> 3;    // 1 or 2
                for (int ss = 0; ss < nss; ++ss) {
                    int sl = ss * 8 + j;      // < 16
                    int ei = cb + sl;
                    bool valid = ei < e_end;
                    int mxs = __shfl(mm.x, sl, 64);
                    int mys = __shfl(mm.y, sl, 64);
                    int r = mys & 3, st = (mys >> 2) & 3, tb = mys >> 6;
                    const float4* kp = (const float4*)(KV + (size_t)mxs * 256 + h * 16);
                    const float4* tp = (const float4*)(ktv + (size_t)tb * 256 + h * 16);
                    float4 k0 = kp[0], k1 = kp[1], k2 = kp[2], k3 = kp[3];
                    float4 t0 = tp[0], t1 = tp[1], t2 = tp[2], t3 = tp[3];
                    const float* qa = qA + h * 68 + r * 17;   // conflict-free banks
                    float sv = (k0.x + t0.x) * qa[0]  + (k0.y + t0.y) * qa[1]
                             + (k0.z + t0.z) * qa[2]  + (k0.w + t0.w) * qa[3]
                             + (k1.x + t1.x) * qa[4]  + (k1.y + t1.y) * qa[5]
                             + (k1.z + t1.z) * qa[6]  + (k1.w + t1.w) * qa[7]
                             + (k2.x + t2.x) * qa[8]  + (k2.y + t2.y) * qa[9]
                             + (k2.z + t2.z) * qa[10] + (k2.w + t2.w) * qa[11]
                             + (k3.x + t3.x) * qa[12] + (k3.y + t3.y) * qa[13]
                             + (k3.z + t3.z) * qa[14] + (k3.w + t3.w) * qa[15];
                    float pri = rel_pri[((tt * 4 + r) * 3 + st) * 8 + h];
                    float p = valid ? __expf(sv * pri * 0.25f) : 0.f;
                    pl[ss * 64 + lane] = p;   // pl[sl*8 + h] in [0,128)
                    ls += p;
                }
                // ---- aggregation: serial over chunk edges, v gathered coalesced ----
                int mx = mm.x, my = mm.y;
                #pragma unroll 4
                for (int i = 0; i < cdeg; ++i) {
                    int src  = __shfl(mx, i, 64);
                    int code = __shfl(my, i, 64);
                    int r = code & 3;
                    float pv = pl[i * 8 + h2];   // broadcast within 8-lane groups
                    float2 v1 = *(const float2*)(KV + (size_t)src * 256 + 128 + d0);
                    float2 v2 = *(const float2*)(ktv + (size_t)(code >> 6) * 256 + 128 + d0);
                    float vx = pv * (v1.x + v2.x);
                    float vy = pv * (v1.y + v2.y);
                    rmask |= (1 << r);
                    switch (r) {
                        case 0: a0v.x += vx; a0v.y += vy; break;
                        case 1: a1v.x += vx; a1v.y += vy; break;
                        case 2: a2v.x += vx; a2v.y += vy; break;
                        default: a3v.x += vx; a3v.y += vy; break;
                    }
                }
            }

            // ---- softmax denominator ----
            ls += __shfl_xor(ls, 8, 64);
            ls += __shfl_xor(ls, 16, 64);
            ls += __shfl_xor(ls, 32, 64);
            float lst = __shfl(ls, h2, 64);        // lane h2 holds total for head h2
            float iv = (lst > 0.f) ? (1.f / lst) : 0.f;

            // ---- epilogue: shfl acc + 2x ds_read_b128 per relation from Mt ----
            float o0 = 0.f, o1 = 0.f;
            #pragma unroll
            for (int r = 0; r < 4; ++r) {
                if (rmask & (1 << r)) {
                    float sx[16];
                    #pragma unroll
                    for (int m = 0; m < 8; ++m) {
                        float ax, ay;
                        if (r == 0)      { ax = __shfl(a0v.x, h2 * 8 + m, 64); ay = __shfl(a0v.y, h2 * 8 + m, 64); }
                        else if (r == 1) { ax = __shfl(a1v.x, h2 * 8 + m, 64); ay = __shfl(a1v.y, h2 * 8 + m, 64); }
                        else if (r == 2) { ax = __shfl(a2v.x, h2 * 8 + m, 64); ay = __shfl(a2v.y, h2 * 8 + m, 64); }
                        else             { ax = __shfl(a3v.x, h2 * 8 + m, 64); ay = __shfl(a3v.y, h2 * 8 + m, 64); }
                        sx[2 * m] = ax; sx[2 * m + 1] = ay;
                    }
                    int b0 = r * 2584 + 324 * h2 + 20 * cp;   // 16B-aligned
                    const float4* M0 = (const float4*)&Mt[b0];
                    float4 x0 = M0[0], x1 = M0[1], x2 = M0[2], x3 = M0[3];
                    o0 += sx[0]*x0.x + sx[1]*x0.y + sx[2]*x0.z + sx[3]*x0.w
                        + sx[4]*x1.x + sx[5]*x1.y + sx[6]*x1.z + sx[7]*x1.w
                        + sx[8]*x2.x + sx[9]*x2.y + sx[10]*x2.z + sx[11]*x2.w
                        + sx[12]*x3.x + sx[13]*x3.y + sx[14]*x3.z + sx[15]*x3.w;
                    const float4* M1 = (const float4*)&Mt[b0 + 20];
                    float4 y0 = M1[0], y1 = M1[1], y2 = M1[2], y3 = M1[3];
                    o1 += sx[0]*y0.x + sx[1]*y0.y + sx[2]*y0.z + sx[3]*y0.w
                        + sx[4]*y1.x + sx[5]*y1.y + sx[6]*y1.z + sx[7]*y1.w
                        + sx[8]*y2.x + sx[9]*y2.y + sx[10]*y2.z + sx[11]*y2.w
                        + sx[12]*y3.x + sx[13]*y3.y + sx[14]*y3.z + sx[15]*y3.w;
                }
            }
            o0 *= iv; o1 *= iv;
            // exact gelu
            o0 = 0.5f * o0 * (1.f + erff(o0 * 0.7071067811865475f));
            o1 = 0.5f * o1 * (1.f + erff(o1 * 0.7071067811865475f));
            *(float2*)(h_out + (size_t)n * 128 + d0) = make_float2(o0, o1);
        }
    }
}

// ---------------- launcher ----------------
extern "C" void kernel_launch(void* const* d_in, const int* in_sizes, int n_in,
                              void* d_out, int out_size, void* d_ws, size_t ws_size,
                              hipStream_t stream) {
    const float* node_feature = (const float*)d_in[0];
    const int*   node_type    = (const int*)d_in[1];
    const int*   edge_index   = (const int*)d_in[2];   // [2,E]: src then tgt
    const int*   edge_type    = (const int*)d_in[3];
    const int*   edge_time    = (const int*)d_in[4];
    const float* adapt_w      = (const float*)d_in[5];
    const float* adapt_b      = (const float*)d_in[6];
    const float* Wk           = (const float*)d_in[7];
    const float* bk           = (const float*)d_in[8];
    const float* Wq           = (const float*)d_in[9];
    const float* bq           = (const float*)d_in[10];
    const float* Wv           = (const float*)d_in[11];
    const float* bv           = (const float*)d_in[12];
    const float* Wa           = (const float*)d_in[13];
    const float* ba           = (const float*)d_in[14];
    const float* rel_pri      = (const float*)d_in[15];
    const float* rel_att      = (const float*)d_in[16];
    const float* rel_msg      = (const float*)d_in[17];
    const float* skip         = (const float*)d_in[18];
    const float* rte_w        = (const float*)d_in[19];
    const float* rte_b        = (const float*)d_in[20];
    float* out = (float*)d_out;

    const size_t ND = (size_t)NN * 128;
    float* Qn     = (float*)d_ws;            // N*128 (reused as h buffer)
    float* KV     = Qn + ND;                 // N*256 (k|v per row)
    float* rtab   = KV + 2 * ND;             // 240*256
    float* rproj  = rtab + 240 * 256;        // 240*128
    float* ktv    = rproj + 240 * 128;       // 720*256 (k|v per row)
    int*   cnt    = (int*)(ktv + 720 * 256);
    int*   fill   = cnt + NN;
    int*   row_st = fill + NN;               // NN+1 (+pad)
    int*   order  = row_st + NN + 4;         // NN
    int*   tcnt   = order + NN;              // 3 (+pad)
    int*   fill3  = tcnt + 4;                // 3 (+pad)
    int4*  meta   = (int4*)(fill3 + 4);      // EE int4
    // total ~165 MB

    const int* esrc = edge_index;
    const int* etgt = edge_index + EE;

    hipMemsetAsync(cnt, 0, 2 * NN * sizeof(int), stream);
    hipMemsetAsync(tcnt, 0, 8 * sizeof(int), stream);
    rte_tab_kernel<<<240, 256, 0, stream>>>(rtab);
    hist_kernel<<<(EE + 255) / 256, 256, 0, stream>>>(etgt, cnt);
    scan_kernel<<<1, 1024, 0, stream>>>(cnt, row_st);
    scatter_meta_kernel<<<(EE + 255) / 256, 256, 0, stream>>>(esrc, etgt, edge_type,
                                                              edge_time, node_type,
                                                              row_st, fill, meta);
    node_hist_kernel<<<(NN + 255) / 256, 256, 0, stream>>>(node_type, tcnt);
    node_scatter_kernel<<<(NN + 255) / 256, 256, 0, stream>>>(node_type, tcnt, fill3, order);

    // input adaptation: x = tanh(typed_linear(node_feature))
    typed_lin_kernel<0><<<NN / 32, 256, 0, stream>>>(node_feature, node_type, order,
                                                     adapt_w, adapt_b, nullptr, out);

    for (int l = 0; l < 2; ++l) {
        const float* Wk_l = Wk + l * 49152;  const float* bk_l = bk + l * 384;
        const float* Wq_l = Wq + l * 49152;  const float* bq_l = bq + l * 384;
        const float* Wv_l = Wv + l * 49152;  const float* bv_l = bv + l * 384;
        const float* Wa_l = Wa + l * 49152;  const float* ba_l = ba + l * 384;
        const float* pri_l = rel_pri + l * 288;
        const float* att_l = rel_att + l * 8192;
        const float* msg_l = rel_msg + l * 8192;
        const float* skip_l = skip + l * 3;
        const float* rte_w_l = rte_w + l * 32768;
        const float* rte_b_l = rte_b + l * 128;

        rte_proj_kernel<<<240, 128, 0, stream>>>(rtab, rte_w_l, rte_b_l, rproj);
        ktv_kernel<<<720, 128, 0, stream>>>(rproj, Wk_l, Wv_l, ktv);
        qkv_kernel<<<NN / 32, 256, 0, stream>>>(out, node_type, order, Wq_l, bq_l,
                                                Wk_l, bk_l, Wv_l, bv_l, Qn, KV);
        edge_kernel<<<(NN + 63) / 64, 1024, 0, stream>>>(Qn, KV, ktv, meta, node_type,
                                                         pri_l, att_l, msg_l, row_st,
                                                         Qn /* h overwrites Qn: safe */);
        typed_lin_kernel<1><<<NN / 32, 256, 0, stream>>>(Qn, node_type, order, Wa_l, ba_l,
                                                         skip_l, out);
    }
}

// Round 11
// 1564.384 us; speedup vs baseline: 1.2268x; 1.0060x over previous
//
#include <hip/hip_runtime.h>
#include <math.h>

#define NN 100000
#define EE 500000

// ---------------- RTE sinusoid table [240, 256] ----------------
__global__ void rte_tab_kernel(float* __restrict__ tab) {
    int p = blockIdx.x;      // 0..239
    int j = threadIdx.x;     // 0..255
    int m = j >> 1;
    // replicate fp32 overflow: 10000^(2m) -> inf for 2m >= 10 in fp32
    float pf = (float)pow(10000.0, (double)(2 * m));
    float dv = 1.0f / (pf / 128.0f / 2.0f);
    float ang = (float)p * dv;
    const float s = 0.08838834764831845f; // 1/sqrt(128)
    float v = (j & 1) ? (cosf(ang) * s) : (sinf(ang) * s);
    tab[p * 256 + j] = v;
}

// ---------------- rte_proj[p,c] = rte_tab[p,:] @ rte_w + rte_b ----------------
__global__ void rte_proj_kernel(const float* __restrict__ tab,
                                const float* __restrict__ rte_w,
                                const float* __restrict__ rte_b,
                                float* __restrict__ proj) {
    __shared__ float row[256];
    int p = blockIdx.x;           // 240
    int c = threadIdx.x;          // 128
    for (int i = threadIdx.x; i < 256; i += 128) row[i] = tab[p * 256 + i];
    __syncthreads();
    float acc = rte_b[c];
    #pragma unroll 8
    for (int q = 0; q < 256; ++q) acc += row[q] * rte_w[q * 128 + c];
    proj[p * 128 + c] = acc;
}

// ---------------- ktv[b][0:128]=proj@Wk[t], ktv[b][128:256]=proj@Wv[t] ----------------
__global__ void ktv_kernel(const float* __restrict__ proj,
                           const float* __restrict__ Wk,
                           const float* __restrict__ Wv,
                           float* __restrict__ ktv) {
    __shared__ float row[128];
    int b = blockIdx.x;           // 720 = t*240 + p
    int t = b / 240, p = b % 240;
    int c = threadIdx.x;          // 128
    row[c] = proj[p * 128 + c];
    __syncthreads();
    const float* wk = Wk + t * 16384 + c;
    const float* wv = Wv + t * 16384 + c;
    float ak = 0.f, av = 0.f;
    #pragma unroll 8
    for (int q = 0; q < 128; ++q) {
        float rv = row[q];
        ak += rv * wk[q * 128];
        av += rv * wv[q * 128];
    }
    ktv[(size_t)b * 256 + c] = ak;
    ktv[(size_t)b * 256 + 128 + c] = av;
}

// ---------------- CSR build (edges grouped by target) ----------------
__global__ void hist_kernel(const int* __restrict__ tgt, int* __restrict__ cnt) {
    int e = blockIdx.x * blockDim.x + threadIdx.x;
    if (e < EE) atomicAdd(&cnt[tgt[e]], 1);
}

__global__ void scan_kernel(const int* __restrict__ cnt, int* __restrict__ row_start) {
    __shared__ int sdata[1024];
    __shared__ int s_running;
    if (threadIdx.x == 0) s_running = 0;
    __syncthreads();
    for (int base = 0; base < NN; base += 1024) {
        int i = base + (int)threadIdx.x;
        int v = (i < NN) ? cnt[i] : 0;
        sdata[threadIdx.x] = v;
        __syncthreads();
        int acc = v;
        for (int off = 1; off < 1024; off <<= 1) {
            int t = (threadIdx.x >= (unsigned)off) ? sdata[threadIdx.x - off] : 0;
            __syncthreads();
            acc += t;
            sdata[threadIdx.x] = acc;
            __syncthreads();
        }
        int run = s_running;
        if (i < NN) row_start[i] = run + acc - v;   // exclusive
        __syncthreads();
        if (threadIdx.x == 1023) s_running = run + sdata[1023];
        __syncthreads();
    }
    if (threadIdx.x == 0) row_start[NN] = s_running;
}

// scatter + meta fused: meta[pos] = {src, (tb<<6)|(tt<<4)|(st<<2)|r, tgt, 0}
__global__ void scatter_meta_kernel(const int* __restrict__ esrc,
                                    const int* __restrict__ etgt,
                                    const int* __restrict__ etype,
                                    const int* __restrict__ etime,
                                    const int* __restrict__ node_type,
                                    const int* __restrict__ row_start,
                                    int* __restrict__ fill,
                                    int4* __restrict__ meta) {
    int e = blockIdx.x * blockDim.x + threadIdx.x;
    if (e < EE) {
        int tgt = etgt[e];
        int src = esrc[e];
        int r = etype[e];
        int tm = etime[e];
        int st = node_type[src];
        int tt = node_type[tgt];
        int tb = st * 240 + tm;
        int pos = row_start[tgt] + atomicAdd(&fill[tgt], 1);
        meta[pos] = make_int4(src, (tb << 6) | (tt << 4) | (st << 2) | r, tgt, 0);
    }
}

// ---------------- node counting sort by type (3 bins) ----------------
__global__ void node_hist_kernel(const int* __restrict__ nt, int* __restrict__ tcnt) {
    __shared__ int lc[3];
    if (threadIdx.x < 3) lc[threadIdx.x] = 0;
    __syncthreads();
    int i = blockIdx.x * blockDim.x + threadIdx.x;
    if (i < NN) atomicAdd(&lc[nt[i]], 1);
    __syncthreads();
    if (threadIdx.x < 3) atomicAdd(&tcnt[threadIdx.x], lc[threadIdx.x]);
}

__global__ void node_scatter_kernel(const int* __restrict__ nt,
                                    const int* __restrict__ tcnt,
                                    int* __restrict__ fill3,
                                    int* __restrict__ order) {
    __shared__ int lc[3], lbase[3], lfill[3];
    if (threadIdx.x < 3) { lc[threadIdx.x] = 0; lfill[threadIdx.x] = 0; }
    __syncthreads();
    int i = blockIdx.x * blockDim.x + threadIdx.x;
    int t = -1;
    if (i < NN) { t = nt[i]; atomicAdd(&lc[t], 1); }
    __syncthreads();
    if (threadIdx.x < 3) lbase[threadIdx.x] = atomicAdd(&fill3[threadIdx.x], lc[threadIdx.x]);
    __syncthreads();
    if (i < NN) {
        int rank = atomicAdd(&lfill[t], 1);
        int tb = (t == 0) ? 0 : ((t == 1) ? tcnt[0] : tcnt[0] + tcnt[1]);
        order[tb + lbase[t] + rank] = i;
    }
}

// ---------------- typed linear over type-sorted nodes ----------------
template <int MODE>
__global__ __launch_bounds__(256) void typed_lin_kernel(
    const float* __restrict__ in, const int* __restrict__ nt,
    const int* __restrict__ order,
    const float* __restrict__ W, const float* __restrict__ b,
    const float* __restrict__ skip, float* __restrict__ out) {
    __shared__ float xs[32][128];
    __shared__ int rows[32];
    __shared__ int sty[32];
    int nb = blockIdx.x * 32;
    if (threadIdx.x < 32) {
        int r = order[nb + threadIdx.x];
        rows[threadIdx.x] = r;
        sty[threadIdx.x] = nt[r];
    }
    __syncthreads();
    for (int i = threadIdx.x; i < 1024; i += 256) {
        int nl = i >> 5, e4 = i & 31;
        *(float4*)&xs[nl][e4 * 4] = *(const float4*)(in + (size_t)rows[nl] * 128 + e4 * 4);
    }
    __syncthreads();
    int col = threadIdx.x & 127;
    int ng  = (threadIdx.x >> 7) * 16;
    int t0 = sty[ng];
    bool uni = true;
    #pragma unroll
    for (int ii = 1; ii < 16; ++ii) uni &= (sty[ng + ii] == t0);
    if (uni) {
        const float* w = W + t0 * 16384 + col;
        float bv = b[t0 * 128 + col];
        float alpha = (MODE == 1) ? (1.f / (1.f + __expf(-skip[t0]))) : 0.f;
        float acc[16];
        #pragma unroll
        for (int ii = 0; ii < 16; ++ii) acc[ii] = bv;
        for (int k0 = 0; k0 < 128; k0 += 4) {
            float w0 = w[(k0 + 0) * 128];
            float w1 = w[(k0 + 1) * 128];
            float w2 = w[(k0 + 2) * 128];
            float w3 = w[(k0 + 3) * 128];
            #pragma unroll
            for (int ii = 0; ii < 16; ++ii) {
                float4 xv = *(const float4*)&xs[ng + ii][k0];
                acc[ii] += xv.x * w0 + xv.y * w1 + xv.z * w2 + xv.w * w3;
            }
        }
        #pragma unroll
        for (int ii = 0; ii < 16; ++ii) {
            size_t gi = (size_t)rows[ng + ii] * 128 + col;
            if (MODE == 0) out[gi] = tanhf(acc[ii]);
            else           out[gi] = alpha * acc[ii] + (1.f - alpha) * out[gi];
        }
    } else {
        for (int ii = 0; ii < 16; ++ii) {
            int nl = ng + ii;
            int t = sty[nl];
            const float* w = W + t * 16384 + col;
            float acc = b[t * 128 + col];
            #pragma unroll 8
            for (int k = 0; k < 128; ++k) acc += xs[nl][k] * w[k * 128];
            size_t gi = (size_t)rows[nl] * 128 + col;
            if (MODE == 0) out[gi] = tanhf(acc);
            else {
                float alpha = 1.f / (1.f + __expf(-skip[t]));
                out[gi] = alpha * acc + (1.f - alpha) * out[gi];
            }
        }
    }
}

// ---------------- fused Q/K/V typed projections; K/V interleaved per row ----------------
__global__ __launch_bounds__(256) void qkv_kernel(
    const float* __restrict__ x, const int* __restrict__ nt,
    const int* __restrict__ order,
    const float* __restrict__ Wq, const float* __restrict__ bq,
    const float* __restrict__ Wk, const float* __restrict__ bk,
    const float* __restrict__ Wv, const float* __restrict__ bv,
    float* __restrict__ Qn, float* __restrict__ KV) {
    __shared__ float xs[32][128];
    __shared__ int rows[32];
    __shared__ int sty[32];
    int nb = blockIdx.x * 32;
    if (threadIdx.x < 32) {
        int r = order[nb + threadIdx.x];
        rows[threadIdx.x] = r;
        sty[threadIdx.x] = nt[r];
    }
    __syncthreads();
    for (int i = threadIdx.x; i < 1024; i += 256) {
        int nl = i >> 5, e4 = i & 31;
        *(float4*)&xs[nl][e4 * 4] = *(const float4*)(x + (size_t)rows[nl] * 128 + e4 * 4);
    }
    __syncthreads();
    int col = threadIdx.x & 127;
    int ng  = (threadIdx.x >> 7) * 16;
    int t0 = sty[ng];
    bool uni = true;
    #pragma unroll
    for (int ii = 1; ii < 16; ++ii) uni &= (sty[ng + ii] == t0);
    if (uni) {
        const float* wq = Wq + t0 * 16384 + col;
        const float* wk = Wk + t0 * 16384 + col;
        const float* wv = Wv + t0 * 16384 + col;
        float bqv = bq[t0 * 128 + col];
        float bkv = bk[t0 * 128 + col];
        float bvv = bv[t0 * 128 + col];
        float aq[16], ak[16], av[16];
        #pragma unroll
        for (int ii = 0; ii < 16; ++ii) { aq[ii] = bqv; ak[ii] = bkv; av[ii] = bvv; }
        for (int k0 = 0; k0 < 128; k0 += 4) {
            float q0 = wq[(k0 + 0) * 128], q1 = wq[(k0 + 1) * 128];
            float q2 = wq[(k0 + 2) * 128], q3 = wq[(k0 + 3) * 128];
            float k0w = wk[(k0 + 0) * 128], k1w = wk[(k0 + 1) * 128];
            float k2w = wk[(k0 + 2) * 128], k3w = wk[(k0 + 3) * 128];
            float v0 = wv[(k0 + 0) * 128], v1 = wv[(k0 + 1) * 128];
            float v2 = wv[(k0 + 2) * 128], v3 = wv[(k0 + 3) * 128];
            #pragma unroll
            for (int ii = 0; ii < 16; ++ii) {
                float4 xv = *(const float4*)&xs[ng + ii][k0];
                aq[ii] += xv.x * q0 + xv.y * q1 + xv.z * q2 + xv.w * q3;
                ak[ii] += xv.x * k0w + xv.y * k1w + xv.z * k2w + xv.w * k3w;
                av[ii] += xv.x * v0 + xv.y * v1 + xv.z * v2 + xv.w * v3;
            }
        }
        #pragma unroll
        for (int ii = 0; ii < 16; ++ii) {
            size_t row = (size_t)rows[ng + ii];
            Qn[row * 128 + col] = aq[ii];
            KV[row * 256 + col] = ak[ii];
            KV[row * 256 + 128 + col] = av[ii];
        }
    } else {
        for (int ii = 0; ii < 16; ++ii) {
            int nl = ng + ii;
            int t = sty[nl];
            const float* wq = Wq + t * 16384 + col;
            const float* wk = Wk + t * 16384 + col;
            const float* wv = Wv + t * 16384 + col;
            float aq = bq[t * 128 + col];
            float ak = bk[t * 128 + col];
            float av = bv[t * 128 + col];
            #pragma unroll 4
            for (int k = 0; k < 128; ++k) {
                float xv = xs[nl][k];
                aq += xv * wq[k * 128];
                ak += xv * wk[k * 128];
                av += xv * wv[k * 128];
            }
            size_t row = (size_t)rows[nl];
            Qn[row * 128 + col] = aq;
            KV[row * 256 + col] = ak;
            KV[row * 256 + 128 + col] = av;
        }
    }
}

// ---------------- fused score + softmax + aggregation, LDS-staged tables ----------------
// R11 = R8 body (chunk-32, pair-prologue, both HW-proven) at 768 threads.
// Rationale from R10 counters: occupancy 18->34% bought -57us, but 1024-thread
// blocks clamp VGPR to 64 (R4 AND R10) -> 213 MB spill traffic (~+110us tax),
// and chunk-16 doubled meta passes. 768 threads = 12 waves:
//   LDS = At 32768 + Mt 41344 + scr 12*1344*4 = 138624 B -> 1 block/CU,
//   12 waves/CU (37.5% nominal > R10's measured 34.5%), and the compiler's
//   natural ~120 VGPR allocation (proven at 512 threads, R7/R8) -> NO spills.
// Each wave: 2 pairs of nodes (4 nodes); grid = ceil(NN/48).
// Mt layout addr(r,h,c,i) = r*2584 + 324h + 20c + i (R7-proven, injective).
__global__ __launch_bounds__(768) void edge_kernel(
    const float* __restrict__ Qn, const float* __restrict__ KV,
    const float* __restrict__ ktv, const int4* __restrict__ meta,
    const int* __restrict__ node_type,
    const float* __restrict__ rel_pri, const float* __restrict__ rel_att,
    const float* __restrict__ rel_msg, const int* __restrict__ row_start,
    float* __restrict__ h_out) {
    __shared__ float At[8192];        // At[l*512 + (r*8+h)*16 + k]      (32768 B)
    __shared__ float Mt[10336];       // Mt[r*2584 + 324h + 20c + i]     (41344 B)
    __shared__ float scr[12][1344];   // per wave: qA0[544] qA1[544] pl[256]

    int tid = threadIdx.x;
    // ---- stage tables (once per block; 768 threads, 3 passes) ----
    for (int g0 = tid * 4; g0 < 8192; g0 += 3072) {
        float4 a = *(const float4*)(rel_att + g0);
        int la = g0 & 15, ka = (g0 >> 4) & 15, rh = g0 >> 8;
        At[(la + 0) * 512 + rh * 16 + ka] = a.x;
        At[(la + 1) * 512 + rh * 16 + ka] = a.y;
        At[(la + 2) * 512 + rh * 16 + ka] = a.z;
        At[(la + 3) * 512 + rh * 16 + ka] = a.w;
        float4 m = *(const float4*)(rel_msg + g0);
        int cm = g0 & 15, im = (g0 >> 4) & 15, hm = (g0 >> 8) & 7, rm = g0 >> 11;
        int rb = rm * 2584 + 324 * hm + 20 * cm + im;
        Mt[rb]      = m.x;
        Mt[rb + 20] = m.y;
        Mt[rb + 40] = m.z;
        Mt[rb + 60] = m.w;
    }
    __syncthreads();   // the ONLY barrier; everything below is wave-independent

    int w = tid >> 6;             // 0..11
    int lane = tid & 63;
    float* qA0 = scr[w];          // [h*68 + r*17 + k]
    float* qA1 = scr[w] + 544;
    float* pl  = scr[w] + 1088;   // 256 floats: p for 32 edges x 8 heads

    int hE = lane >> 4;               // head slice 0..3 (even-u), +4 for odd-u
    int j  = lane >> 3, h = lane & 7; // score mapping: lane = j*8 + h
    int h2 = lane >> 3, d0 = lane * 2;// aggr mapping: head h2, dims d0,d0+1
    int cp = (lane & 7) * 2;          // epilogue col pair within head
    int kk = lane & 15;               // prologue k index
    int nbase = blockIdx.x * 48 + w * 4;

    for (int pr = 0; pr < 2; ++pr) {
        int n0 = nbase + 2 * pr;
        if (n0 >= NN) break;          // NN even: n0 < NN implies n0+1 < NN

        // q slices for BOTH nodes into registers
        const float4* q0p  = (const float4*)(Qn + (size_t)n0 * 128 + hE * 16);
        const float4* q0p2 = (const float4*)(Qn + (size_t)n0 * 128 + 64 + hE * 16);
        const float4* q1p  = (const float4*)(Qn + (size_t)(n0 + 1) * 128 + hE * 16);
        const float4* q1p2 = (const float4*)(Qn + (size_t)(n0 + 1) * 128 + 64 + hE * 16);
        float4 aE0 = q0p[0],  aE1 = q0p[1],  aE2 = q0p[2],  aE3 = q0p[3];
        float4 aO0 = q0p2[0], aO1 = q0p2[1], aO2 = q0p2[2], aO3 = q0p2[3];
        float4 bE0 = q1p[0],  bE1 = q1p[1],  bE2 = q1p[2],  bE3 = q1p[3];
        float4 bO0 = q1p2[0], bO1 = q1p2[1], bO2 = q1p2[2], bO3 = q1p2[3];

        int eb0 = row_start[n0];
        int eb1 = row_start[n0 + 1];
        int eb2 = row_start[n0 + 2];

        // ---- pair-prologue: shared At reads feed two dot products ----
        #pragma unroll
        for (int u = 0; u < 8; ++u) {
            int f = u * 64 + lane;    // f = (r*8+h)*16 + k; h=(u&1)*4+hE, r=u>>1
            const float* a = &At[f];
            float t0 = a[0*512],  t1 = a[1*512],  t2 = a[2*512],  t3 = a[3*512];
            float t4 = a[4*512],  t5 = a[5*512],  t6 = a[6*512],  t7 = a[7*512];
            float t8 = a[8*512],  t9 = a[9*512],  t10 = a[10*512], t11 = a[11*512];
            float t12 = a[12*512], t13 = a[13*512], t14 = a[14*512], t15 = a[15*512];
            float4 qa0 = (u & 1) ? aO0 : aE0, qa1 = (u & 1) ? aO1 : aE1;
            float4 qa2 = (u & 1) ? aO2 : aE2, qa3 = (u & 1) ? aO3 : aE3;
            float4 qb0 = (u & 1) ? bO0 : bE0, qb1 = (u & 1) ? bO1 : bE1;
            float4 qb2 = (u & 1) ? bO2 : bE2, qb3 = (u & 1) ? bO3 : bE3;
            float v0 = t0*qa0.x + t1*qa0.y + t2*qa0.z + t3*qa0.w
                     + t4*qa1.x + t5*qa1.y + t6*qa1.z + t7*qa1.w
                     + t8*qa2.x + t9*qa2.y + t10*qa2.z + t11*qa2.w
                     + t12*qa3.x + t13*qa3.y + t14*qa3.z + t15*qa3.w;
            float v1 = t0*qb0.x + t1*qb0.y + t2*qb0.z + t3*qb0.w
                     + t4*qb1.x + t5*qb1.y + t6*qb1.z + t7*qb1.w
                     + t8*qb2.x + t9*qb2.y + t10*qb2.z + t11*qb2.w
                     + t12*qb3.x + t13*qb3.y + t14*qb3.z + t15*qb3.w;
            int hh = (u & 1) * 4 + hE;
            int rr = u >> 1;
            int idx = hh * 68 + rr * 17 + kk;
            qA0[idx] = v0;
            qA1[idx] = v1;
        }

        // ---- process the two nodes sequentially (R7/R8-proven body) ----
        for (int s = 0; s < 2; ++s) {
            int n = n0 + s;
            int e_beg = s ? eb1 : eb0;
            int e_end = s ? eb2 : eb1;
            const float* qA = s ? qA1 : qA0;
            int tt = node_type[n];

            int4 mm = make_int4(0, 0, 0, 0);
            if (lane < 32 && e_beg + lane < e_end) mm = meta[e_beg + lane];

            float ls = 0.f;
            float2 a0v = {0.f,0.f}, a1v = {0.f,0.f}, a2v = {0.f,0.f}, a3v = {0.f,0.f};
            int rmask = 0;

            for (int cb = e_beg; cb < e_end; cb += 32) {
                if (cb > e_beg) {
                    mm = make_int4(0, 0, 0, 0);
                    if (lane < 32 && cb + lane < e_end) mm = meta[cb + lane];
                }
                int cdeg = min(32, e_end - cb);
                // ---- score: 8 edges x 8 heads per pass; p -> wave-private LDS ----
                int nss = (cdeg + 7) >> 3;
                for (int ss = 0; ss < nss; ++ss) {
                    int sl = ss * 8 + j;
                    int ei = cb + sl;
                    bool valid = ei < e_end;
                    int mxs = __shfl(mm.x, sl, 64);
                    int mys = __shfl(mm.y, sl, 64);
                    int r = mys & 3, st = (mys >> 2) & 3, tb = mys >> 6;
                    const float4* kp = (const float4*)(KV + (size_t)mxs * 256 + h * 16);
                    const float4* tp = (const float4*)(ktv + (size_t)tb * 256 + h * 16);
                    float4 k0 = kp[0], k1 = kp[1], k2 = kp[2], k3 = kp[3];
                    float4 t0 = tp[0], t1 = tp[1], t2 = tp[2], t3 = tp[3];
                    const float* qa = qA + h * 68 + r * 17;   // conflict-free banks
                    float sv = (k0.x + t0.x) * qa[0]  + (k0.y + t0.y) * qa[1]
                             + (k0.z + t0.z) * qa[2]  + (k0.w + t0.w) * qa[3]
                             + (k1.x + t1.x) * qa[4]  + (k1.y + t1.y) * qa[5]
                             + (k1.z + t1.z) * qa[6]  + (k1.w + t1.w) * qa[7]
                             + (k2.x + t2.x) * qa[8]  + (k2.y + t2.y) * qa[9]
                             + (k2.z + t2.z) * qa[10] + (k2.w + t2.w) * qa[11]
                             + (k3.x + t3.x) * qa[12] + (k3.y + t3.y) * qa[13]
                             + (k3.z + t3.z) * qa[14] + (k3.w + t3.w) * qa[15];
                    float pri = rel_pri[((tt * 4 + r) * 3 + st) * 8 + h];
                    float p = valid ? __expf(sv * pri * 0.25f) : 0.f;
                    pl[ss * 64 + lane] = p;   // pl[sl*8 + h]: conflict-free
                    ls += p;
                }
                // ---- aggregation: serial over chunk edges, v gathered coalesced ----
                int mx = mm.x, my = mm.y;
                #pragma unroll 4
                for (int i = 0; i < cdeg; ++i) {
                    int src  = __shfl(mx, i, 64);
                    int code = __shfl(my, i, 64);
                    int r = code & 3;
                    float pv = pl[i * 8 + h2];   // broadcast within 8-lane groups
                    float2 v1 = *(const float2*)(KV + (size_t)src * 256 + 128 + d0);
                    float2 v2 = *(const float2*)(ktv + (size_t)(code >> 6) * 256 + 128 + d0);
                    float vx = pv * (v1.x + v2.x);
                    float vy = pv * (v1.y + v2.y);
                    rmask |= (1 << r);
                    switch (r) {
                        case 0: a0v.x += vx; a0v.y += vy; break;
                        case 1: a1v.x += vx; a1v.y += vy; break;
                        case 2: a2v.x += vx; a2v.y += vy; break;
                        default: a3v.x += vx; a3v.y += vy; break;
                    }
                }
            }

            // ---- softmax denominator ----
            ls += __shfl_xor(ls, 8, 64);
            ls += __shfl_xor(ls, 16, 64);
            ls += __shfl_xor(ls, 32, 64);
            float lst = __shfl(ls, h2, 64);        // lane h2 holds total for head h2
            float iv = (lst > 0.f) ? (1.f / lst) : 0.f;

            // ---- epilogue: shfl acc + 2x ds_read_b128 per relation from Mt ----
            float o0 = 0.f, o1 = 0.f;
            #pragma unroll
            for (int r = 0; r < 4; ++r) {
                if (rmask & (1 << r)) {
                    float sx[16];
                    #pragma unroll
                    for (int m = 0; m < 8; ++m) {
                        float ax, ay;
                        if (r == 0)      { ax = __shfl(a0v.x, h2 * 8 + m, 64); ay = __shfl(a0v.y, h2 * 8 + m, 64); }
                        else if (r == 1) { ax = __shfl(a1v.x, h2 * 8 + m, 64); ay = __shfl(a1v.y, h2 * 8 + m, 64); }
                        else if (r == 2) { ax = __shfl(a2v.x, h2 * 8 + m, 64); ay = __shfl(a2v.y, h2 * 8 + m, 64); }
                        else             { ax = __shfl(a3v.x, h2 * 8 + m, 64); ay = __shfl(a3v.y, h2 * 8 + m, 64); }
                        sx[2 * m] = ax; sx[2 * m + 1] = ay;
                    }
                    int b0 = r * 2584 + 324 * h2 + 20 * cp;   // 16B-aligned
                    const float4* M0 = (const float4*)&Mt[b0];
                    float4 x0 = M0[0], x1 = M0[1], x2 = M0[2], x3 = M0[3];
                    o0 += sx[0]*x0.x + sx[1]*x0.y + sx[2]*x0.z + sx[3]*x0.w
                        + sx[4]*x1.x + sx[5]*x1.y + sx[6]*x1.z + sx[7]*x1.w
                        + sx[8]*x2.x + sx[9]*x2.y + sx[10]*x2.z + sx[11]*x2.w
                        + sx[12]*x3.x + sx[13]*x3.y + sx[14]*x3.z + sx[15]*x3.w;
                    const float4* M1 = (const float4*)&Mt[b0 + 20];
                    float4 y0 = M1[0], y1 = M1[1], y2 = M1[2], y3 = M1[3];
                    o1 += sx[0]*y0.x + sx[1]*y0.y + sx[2]*y0.z + sx[3]*y0.w
                        + sx[4]*y1.x + sx[5]*y1.y + sx[6]*y1.z + sx[7]*y1.w
                        + sx[8]*y2.x + sx[9]*y2.y + sx[10]*y2.z + sx[11]*y2.w
                        + sx[12]*y3.x + sx[13]*y3.y + sx[14]*y3.z + sx[15]*y3.w;
                }
            }
            o0 *= iv; o1 *= iv;
            // exact gelu
            o0 = 0.5f * o0 * (1.f + erff(o0 * 0.7071067811865475f));
            o1 = 0.5f * o1 * (1.f + erff(o1 * 0.7071067811865475f));
            *(float2*)(h_out + (size_t)n * 128 + d0) = make_float2(o0, o1);
        }
    }
}

// ---------------- launcher ----------------
extern "C" void kernel_launch(void* const* d_in, const int* in_sizes, int n_in,
                              void* d_out, int out_size, void* d_ws, size_t ws_size,
                              hipStream_t stream) {
    const float* node_feature = (const float*)d_in[0];
    const int*   node_type    = (const int*)d_in[1];
    const int*   edge_index   = (const int*)d_in[2];   // [2,E]: src then tgt
    const int*   edge_type    = (const int*)d_in[3];
    const int*   edge_time    = (const int*)d_in[4];
    const float* adapt_w      = (const float*)d_in[5];
    const float* adapt_b      = (const float*)d_in[6];
    const float* Wk           = (const float*)d_in[7];
    const float* bk           = (const float*)d_in[8];
    const float* Wq           = (const float*)d_in[9];
    const float* bq           = (const float*)d_in[10];
    const float* Wv           = (const float*)d_in[11];
    const float* bv           = (const float*)d_in[12];
    const float* Wa           = (const float*)d_in[13];
    const float* ba           = (const float*)d_in[14];
    const float* rel_pri      = (const float*)d_in[15];
    const float* rel_att      = (const float*)d_in[16];
    const float* rel_msg      = (const float*)d_in[17];
    const float* skip         = (const float*)d_in[18];
    const float* rte_w        = (const float*)d_in[19];
    const float* rte_b        = (const float*)d_in[20];
    float* out = (float*)d_out;

    const size_t ND = (size_t)NN * 128;
    float* Qn     = (float*)d_ws;            // N*128 (reused as h buffer)
    float* KV     = Qn + ND;                 // N*256 (k|v per row)
    float* rtab   = KV + 2 * ND;             // 240*256
    float* rproj  = rtab + 240 * 256;        // 240*128
    float* ktv    = rproj + 240 * 128;       // 720*256 (k|v per row)
    int*   cnt    = (int*)(ktv + 720 * 256);
    int*   fill   = cnt + NN;
    int*   row_st = fill + NN;               // NN+1 (+pad)
    int*   order  = row_st + NN + 4;         // NN
    int*   tcnt   = order + NN;              // 3 (+pad)
    int*   fill3  = tcnt + 4;                // 3 (+pad)
    int4*  meta   = (int4*)(fill3 + 4);      // EE int4
    // total ~165 MB

    const int* esrc = edge_index;
    const int* etgt = edge_index + EE;

    hipMemsetAsync(cnt, 0, 2 * NN * sizeof(int), stream);
    hipMemsetAsync(tcnt, 0, 8 * sizeof(int), stream);
    rte_tab_kernel<<<240, 256, 0, stream>>>(rtab);
    hist_kernel<<<(EE + 255) / 256, 256, 0, stream>>>(etgt, cnt);
    scan_kernel<<<1, 1024, 0, stream>>>(cnt, row_st);
    scatter_meta_kernel<<<(EE + 255) / 256, 256, 0, stream>>>(esrc, etgt, edge_type,
                                                              edge_time, node_type,
                                                              row_st, fill, meta);
    node_hist_kernel<<<(NN + 255) / 256, 256, 0, stream>>>(node_type, tcnt);
    node_scatter_kernel<<<(NN + 255) / 256, 256, 0, stream>>>(node_type, tcnt, fill3, order);

    // input adaptation: x = tanh(typed_linear(node_feature))
    typed_lin_kernel<0><<<NN / 32, 256, 0, stream>>>(node_feature, node_type, order,
                                                     adapt_w, adapt_b, nullptr, out);

    for (int l = 0; l < 2; ++l) {
        const float* Wk_l = Wk + l * 49152;  const float* bk_l = bk + l * 384;
        const float* Wq_l = Wq + l * 49152;  const float* bq_l = bq + l * 384;
        const float* Wv_l = Wv + l * 49152;  const float* bv_l = bv + l * 384;
        const float* Wa_l = Wa + l * 49152;  const float* ba_l = ba + l * 384;
        const float* pri_l = rel_pri + l * 288;
        const float* att_l = rel_att + l * 8192;
        const float* msg_l = rel_msg + l * 8192;
        const float* skip_l = skip + l * 3;
        const float* rte_w_l = rte_w + l * 32768;
        const float* rte_b_l = rte_b + l * 128;

        rte_proj_kernel<<<240, 128, 0, stream>>>(rtab, rte_w_l, rte_b_l, rproj);
        ktv_kernel<<<720, 128, 0, stream>>>(rproj, Wk_l, Wv_l, ktv);
        qkv_kernel<<<NN / 32, 256, 0, stream>>>(out, node_type, order, Wq_l, bq_l,
                                                Wk_l, bk_l, Wv_l, bv_l, Qn, KV);
        edge_kernel<<<(NN + 47) / 48, 768, 0, stream>>>(Qn, KV, ktv, meta, node_type,
                                                        pri_l, att_l, msg_l, row_st,
                                                        Qn /* h overwrites Qn: safe */);
        typed_lin_kernel<1><<<NN / 32, 256, 0, stream>>>(Qn, node_type, order, Wa_l, ba_l,
                                                         skip_l, out);
    }
}